// Round 10
// baseline (516.122 us; speedup 1.0000x reference)
//
#include <hip/hip_runtime.h>

#define BB 32
#define NN 256
#define NF 16
#define NBLK 1024
#define MAGIC 0x1357913

typedef _Float16 half4 __attribute__((ext_vector_type(4)));
typedef float f32x4 __attribute__((ext_vector_type(4)));

// ws float layout: x0@0, x1@32768, su0@65536, su1@196608, barrier ints @327680
// bar[0]=magic, bar[1..3]=arrive counters, bar[4..6]=release flags.

__device__ __forceinline__ float dot4(float4 a, float4 b, float acc) {
    acc = fmaf(a.x, b.x, acc); acc = fmaf(a.y, b.y, acc);
    acc = fmaf(a.z, b.z, acc); acc = fmaf(a.w, b.w, acc);
    return acc;
}

// Global barrier. Preconditions: all NBLK blocks co-resident (enforced by
// __launch_bounds__(256,4): VGPR<=128 -> 4 blocks/CU x 256 CU = NBLK).
// __syncthreads drains each wave's stores to L2 (compiler emits vmcnt(0)
// before s_barrier); tid0's __threadfence does buffer_wbl2 (whole-L2 flush
// to LLC, covers all threads' landed stores); release/acquire at agent scope
// gives cross-XCD visibility (acquire emits buffer_inv).
__device__ __forceinline__ void gbar(int* bar, int which) {
    __syncthreads();
    if (threadIdx.x == 0) {
        __threadfence();
        const int old = atomicAdd(&bar[1 + which], 1);
        if (old == NBLK - 1) {
            __hip_atomic_store(&bar[4 + which], 1, __ATOMIC_RELEASE,
                               __HIP_MEMORY_SCOPE_AGENT);
        } else {
            while (__hip_atomic_load(&bar[4 + which], __ATOMIC_ACQUIRE,
                                     __HIP_MEMORY_SCOPE_AGENT) == 0)
                __builtin_amdgcn_s_sleep(1);
        }
    }
    __syncthreads();
}

// ONE launch: init + 3 EGNN layers. 1024 blocks x 256 thr; block = (batch b,
// node-octet oct); wave w owns dsts j0=8*oct+w, j1=8*oct+4+w (R8's validated
// 2-dst tile loop verbatim). h lives in LDS (sh8) across layers; su and x
// ping-pong through global with gbar between layers.
// Per 16-src tile, per dst, one v_mfma_f32_16x16x16f16 (lane (g,c)):
//   A-frag: We2[k=4g+i][outfeat=c]  B-frag: m1[src=16t+c][k=4g+i]
//   C-frag: m-hat[outfeat=4g+r][src=c]; self-edge masked in g only
//   (w-path self-term cancels exactly in Sw*xj - Swx).
__global__ __launch_bounds__(256, 4)
void fused_kernel(const float* __restrict__ xs, const float* __restrict__ vs,
                  const float* __restrict__ charges, const float* __restrict__ W_in,
                  const float* __restrict__ b_in, const float* __restrict__ W_v,
                  const float* __restrict__ We1, const float* __restrict__ be1,
                  const float* __restrict__ We2, const float* __restrict__ be2,
                  const float* __restrict__ Wx, const float* __restrict__ Wh1,
                  const float* __restrict__ bh1, float* __restrict__ out,
                  float* __restrict__ ws) {
    __shared__ __align__(16) float sWaT[256];   // Wsrc(l+1)^T (init: Wsrc(0)^T)
    __shared__ __align__(16) float sWbT[256];   // Wdst(l)^T
    __shared__ float sWh1s[512];
    __shared__ __align__(16) float sh8[8][NF];  // block's 8 nodes' h (persistent)
    __shared__ float svd[8][NF];
    __shared__ float sg[8][NF];
    __shared__ float sbe1[NF];

    const int tid  = threadIdx.x;
    const int b    = blockIdx.x >> 5;
    const int oct  = blockIdx.x & 31;
    const int n0l  = 8 * oct;
    const size_t n0 = (size_t)b * NN + n0l;
    const int w    = tid >> 6;
    const int lane = tid & 63;
    const int c    = lane & 15;
    const int g    = lane >> 4;

    float* x0  = ws;
    float* x1  = ws + 32768;
    float* su0 = ws + 65536;
    float* su1 = ws + 196608;
    int*   bar = (int*)(ws + 327680);

    // ---- barrier-state handshake (ws is 0xAA-poisoned every call) ----
    if (blockIdx.x == 0 && tid == 0) {
        bar[1] = 0; bar[2] = 0; bar[3] = 0;
        bar[4] = 0; bar[5] = 0; bar[6] = 0;
        __hip_atomic_store(&bar[0], MAGIC, __ATOMIC_RELEASE, __HIP_MEMORY_SCOPE_AGENT);
    }
    if (tid == 0) {
        while (__hip_atomic_load(&bar[0], __ATOMIC_ACQUIRE,
                                 __HIP_MEMORY_SCOPE_AGENT) != MAGIC)
            __builtin_amdgcn_s_sleep(1);
    }
    __syncthreads();

    // ---- init: h0 (LDS), x0, su0 for this block's 8 nodes ----
    {
        const int f = tid >> 4, k = tid & 15;
        sWaT[k * NF + f] = We1[tid];            // Wsrc(0)^T
    }
    if (tid < 128) {
        const int jd = tid >> 4, f = tid & 15;
        sh8[jd][f] = fmaxf(fmaf(charges[n0 + jd], W_in[f], b_in[f]), 0.f);
    }
    if (tid < 32) {
        const int jd = tid >> 2, q = tid & 3;
        x0[(n0 + jd) * 4 + q] = (q < 3) ? xs[(n0 + jd) * 3 + q] : 0.f;
    }
    __syncthreads();
    if (tid < 128) {
        const int jd = tid >> 4, k = tid & 15;
        const float4* hj = (const float4*)&sh8[jd][0];
        const float4* wt = (const float4*)&sWaT[k * NF];
        float u = dot4(hj[0], wt[0], 0.f);
        u = dot4(hj[1], wt[1], u);
        u = dot4(hj[2], wt[2], u);
        u = dot4(hj[3], wt[3], u);
        su0[(n0 + jd) * NF + k] = u;
    }
    gbar(bar, 0);

    // ---- 3 layers ----
#pragma unroll 1
    for (int l = 0; l < 3; ++l) {
        const int final_layer = (l == 2);
        const float* We1_l = We1 + l * 528;
        const float* We2_l = We2 + l * 256;
        const float* Wv_l  = W_v + l * NF;
        const float* be2_l = be2 + l * NF;
        const float* Wx_l  = Wx  + l * NF;
        const float* Wh1_l = Wh1 + l * 512;
        const float* bh1_l = bh1 + l * NF;
        const float* x_cur  = (l == 1) ? x1 : x0;
        float*       x_nxt  = (l == 0) ? x1 : x0;
        const float* su_cur = (l == 1) ? su1 : su0;
        float*       su_nxt = (l == 0) ? su1 : su0;

        __syncthreads();    // LDS weight-array reuse guard
        {
            const int f = tid >> 4, k = tid & 15;
            sWbT[k * NF + f] = We1_l[256 + tid];            // Wdst(l)^T
            if (!final_layer) sWaT[k * NF + f] = We1[(l + 1) * 528 + tid];
        }
        sWh1s[tid]       = Wh1_l[tid];
        sWh1s[256 + tid] = Wh1_l[256 + tid];
        if (tid < NF) sbe1[tid] = be1[l * NF + tid];
        half4 afrag;
        afrag.x = (_Float16)We2_l[(4 * g + 0) * NF + c];
        afrag.y = (_Float16)We2_l[(4 * g + 1) * NF + c];
        afrag.z = (_Float16)We2_l[(4 * g + 2) * NF + c];
        afrag.w = (_Float16)We2_l[(4 * g + 3) * NF + c];
        const float4 wr4  = *(const float4*)(We1_l + 512 + 4 * g);
        const float4 be2f = *(const float4*)(be2_l + 4 * g);
        const float4 wxf  = *(const float4*)(Wx_l + 4 * g);
        __syncthreads();

        // v_j = be1 + h_j @ Wdst for the block's 8 dsts
        if (tid < 128) {
            const int jd = tid >> 4, k = tid & 15;
            const float4* hj = (const float4*)&sh8[jd][0];
            const float4* wt = (const float4*)&sWbT[k * NF];
            float v = sbe1[k];
            v = dot4(hj[0], wt[0], v);
            v = dot4(hj[1], wt[1], v);
            v = dot4(hj[2], wt[2], v);
            v = dot4(hj[3], wt[3], v);
            svd[jd][k] = v;
        }
        __syncthreads();

        // per-wave dst invariants
        const int j0 = n0l + w, j1 = n0l + 4 + w;
        const float* x_b  = x_cur + (size_t)b * NN * 4;
        const float* su_b = su_cur + (size_t)b * NN * NF;
        const float4 xj0 = *(const float4*)(x_b + 4 * j0);
        const float4 xj1 = *(const float4*)(x_b + 4 * j1);
        const float4 v40 = *(const float4*)&svd[w][4 * g];
        const float4 v41 = *(const float4*)&svd[w + 4][4 * g];

        float Sw0 = 0.f, Swx0 = 0.f, Swy0 = 0.f, Swz0 = 0.f;
        float Sw1 = 0.f, Swx1 = 0.f, Swy1 = 0.f, Swz1 = 0.f;
        float g00 = 0.f, g01 = 0.f, g02 = 0.f, g03 = 0.f;
        float g10 = 0.f, g11 = 0.f, g12 = 0.f, g13 = 0.f;

        const float* su_p = su_b + c * NF + 4 * g;
        const float* x_p  = x_b + 4 * c;

#pragma unroll 2
        for (int t = 0; t < 16; ++t) {
            const float4 u4  = *(const float4*)(su_p + 256 * t);
            const float4 xs4 = *(const float4*)(x_p + 64 * t);
            const f32x4 zc = {0.f, 0.f, 0.f, 0.f};
            const int s = 16 * t + c;
            // ---- dst 0 ----
            {
                const float dx = xj0.x - xs4.x, dy = xj0.y - xs4.y, dz = xj0.z - xs4.z;
                const float r2 = fmaf(dx, dx, fmaf(dy, dy, dz * dz));
                const float m0 = fmaxf(fmaf(r2, wr4.x, u4.x + v40.x), 0.f);
                const float m1 = fmaxf(fmaf(r2, wr4.y, u4.y + v40.y), 0.f);
                const float m2 = fmaxf(fmaf(r2, wr4.z, u4.z + v40.z), 0.f);
                const float m3 = fmaxf(fmaf(r2, wr4.w, u4.w + v40.w), 0.f);
                half4 bfrag;
                bfrag.x = (_Float16)m0; bfrag.y = (_Float16)m1;
                bfrag.z = (_Float16)m2; bfrag.w = (_Float16)m3;
                const f32x4 acc = __builtin_amdgcn_mfma_f32_16x16x16f16(afrag, bfrag, zc, 0, 0, 0);
                const float e0 = fmaxf(acc.x + be2f.x, 0.f);
                const float e1 = fmaxf(acc.y + be2f.y, 0.f);
                const float e2 = fmaxf(acc.z + be2f.z, 0.f);
                const float e3 = fmaxf(acc.w + be2f.w, 0.f);
                float wp = e0 * wxf.x;
                wp = fmaf(e1, wxf.y, wp);
                wp = fmaf(e2, wxf.z, wp);
                wp = fmaf(e3, wxf.w, wp);
                const float gsel = (s != j0) ? 1.f : 0.f;
                g00 = fmaf(e0, gsel, g00);
                g01 = fmaf(e1, gsel, g01);
                g02 = fmaf(e2, gsel, g02);
                g03 = fmaf(e3, gsel, g03);
                Sw0 += wp;
                Swx0 = fmaf(wp, xs4.x, Swx0);
                Swy0 = fmaf(wp, xs4.y, Swy0);
                Swz0 = fmaf(wp, xs4.z, Swz0);
            }
            // ---- dst 1 (reuses u4/xs4) ----
            {
                const float dx = xj1.x - xs4.x, dy = xj1.y - xs4.y, dz = xj1.z - xs4.z;
                const float r2 = fmaf(dx, dx, fmaf(dy, dy, dz * dz));
                const float m0 = fmaxf(fmaf(r2, wr4.x, u4.x + v41.x), 0.f);
                const float m1 = fmaxf(fmaf(r2, wr4.y, u4.y + v41.y), 0.f);
                const float m2 = fmaxf(fmaf(r2, wr4.z, u4.z + v41.z), 0.f);
                const float m3 = fmaxf(fmaf(r2, wr4.w, u4.w + v41.w), 0.f);
                half4 bfrag;
                bfrag.x = (_Float16)m0; bfrag.y = (_Float16)m1;
                bfrag.z = (_Float16)m2; bfrag.w = (_Float16)m3;
                const f32x4 acc = __builtin_amdgcn_mfma_f32_16x16x16f16(afrag, bfrag, zc, 0, 0, 0);
                const float e0 = fmaxf(acc.x + be2f.x, 0.f);
                const float e1 = fmaxf(acc.y + be2f.y, 0.f);
                const float e2 = fmaxf(acc.z + be2f.z, 0.f);
                const float e3 = fmaxf(acc.w + be2f.w, 0.f);
                float wp = e0 * wxf.x;
                wp = fmaf(e1, wxf.y, wp);
                wp = fmaf(e2, wxf.z, wp);
                wp = fmaf(e3, wxf.w, wp);
                const float gsel = (s != j1) ? 1.f : 0.f;
                g10 = fmaf(e0, gsel, g10);
                g11 = fmaf(e1, gsel, g11);
                g12 = fmaf(e2, gsel, g12);
                g13 = fmaf(e3, gsel, g13);
                Sw1 += wp;
                Swx1 = fmaf(wp, xs4.x, Swx1);
                Swy1 = fmaf(wp, xs4.y, Swy1);
                Swz1 = fmaf(wp, xs4.z, Swz1);
            }
        }

        // out-of-loop reductions
#pragma unroll
        for (int off = 1; off < 64; off <<= 1) {
            Sw0  += __shfl_xor(Sw0,  off, 64);  Sw1  += __shfl_xor(Sw1,  off, 64);
            Swx0 += __shfl_xor(Swx0, off, 64);  Swx1 += __shfl_xor(Swx1, off, 64);
            Swy0 += __shfl_xor(Swy0, off, 64);  Swy1 += __shfl_xor(Swy1, off, 64);
            Swz0 += __shfl_xor(Swz0, off, 64);  Swz1 += __shfl_xor(Swz1, off, 64);
        }
#pragma unroll
        for (int off = 1; off < 16; off <<= 1) {
            g00 += __shfl_xor(g00, off, 64);  g10 += __shfl_xor(g10, off, 64);
            g01 += __shfl_xor(g01, off, 64);  g11 += __shfl_xor(g11, off, 64);
            g02 += __shfl_xor(g02, off, 64);  g12 += __shfl_xor(g12, off, 64);
            g03 += __shfl_xor(g03, off, 64);  g13 += __shfl_xor(g13, off, 64);
        }
        if ((lane & 15) == 0) {
            *(float4*)&sg[w][4 * g]     = make_float4(g00, g01, g02, g03);
            *(float4*)&sg[w + 4][4 * g] = make_float4(g10, g11, g12, g13);
        }
        __syncthreads();

        // node epilogue: lanes 0..15 -> j0 (slot w); 32..47 -> j1 (slot w+4)
        const int is0 = (lane < 16);
        const int is1 = (lane >= 32 && lane < 48);
        float hnew = 0.f;
        int slot = 0;
        if (is0 || is1) {
            const int f = lane & 15;
            slot = is0 ? w : (w + 4);
            const int jm   = is0 ? j0 : j1;
            const float SwS = is0 ? Sw0  : Sw1;
            const float SxS = is0 ? Swx0 : Swx1;
            const float SyS = is0 ? Swy0 : Swy1;
            const float SzS = is0 ? Swz0 : Swz1;
            const float4 xjm = is0 ? xj0 : xj1;
            const size_t nj = (size_t)b * NN + jm;
            float hd = bh1_l[f];
            float hv = 0.f;
#pragma unroll
            for (int k = 0; k < NF; ++k) {
                const float hjk = sh8[slot][k];
                hd = fmaf(hjk, sWh1s[k * NF + f], hd);
                hv = fmaf(hjk, Wv_l[k], hv);
            }
#pragma unroll
            for (int k = 0; k < NF; ++k) {
                hd = fmaf(sg[slot][k], sWh1s[(NF + k) * NF + f], hd);
            }
            hnew = sh8[slot][f] + fmaxf(hd, 0.f);
            if (f < 3) {
                const float xc = (f == 0) ? xjm.x : ((f == 1) ? xjm.y : xjm.z);
                const float Sc = (f == 0) ? SxS  : ((f == 1) ? SyS  : SzS);
                const float agg = (SwS * xc - Sc) * (1.f / 255.f);
                const float xnew = xc + agg + vs[nj * 3 + f] * hv;
                if (final_layer) out[nj * 3 + f] = xnew;
                else             x_nxt[nj * 4 + f] = xnew;
            }
            if (!final_layer && f == 3) x_nxt[nj * 4 + 3] = 0.f;
        }
        __syncthreads();                 // all sh8 reads done
        if (is0 || is1) sh8[slot][lane & 15] = hnew;

        if (!final_layer) {
            __syncthreads();             // sh8 fully updated
            // su for the NEXT layer (this block's 8 nodes)
            if (tid < 128) {
                const int jd = tid >> 4, k = tid & 15;
                const float4* hj = (const float4*)&sh8[jd][0];
                const float4* wt = (const float4*)&sWaT[k * NF];
                float u = dot4(hj[0], wt[0], 0.f);
                u = dot4(hj[1], wt[1], u);
                u = dot4(hj[2], wt[2], u);
                u = dot4(hj[3], wt[3], u);
                su_nxt[(n0 + jd) * NF + k] = u;
            }
            gbar(bar, l + 1);
        }
    }
}

extern "C" void kernel_launch(void* const* d_in, const int* in_sizes, int n_in,
                              void* d_out, int out_size, void* d_ws, size_t ws_size,
                              hipStream_t stream) {
    const float* xs      = (const float*)d_in[0];
    const float* vs      = (const float*)d_in[1];
    const float* charges = (const float*)d_in[2];
    const float* W_in    = (const float*)d_in[3];
    const float* b_in    = (const float*)d_in[4];
    const float* W_v     = (const float*)d_in[5];
    const float* We1     = (const float*)d_in[6];
    const float* be1     = (const float*)d_in[7];
    const float* We2     = (const float*)d_in[8];
    const float* be2     = (const float*)d_in[9];
    const float* Wx      = (const float*)d_in[10];
    const float* Wh1     = (const float*)d_in[11];
    const float* bh1     = (const float*)d_in[12];
    // d_in[13]=src, d_in[14]=dst: fully-connected pattern, computed analytically.

    float* ws  = (float*)d_ws;
    float* out = (float*)d_out;

    hipLaunchKernelGGL(fused_kernel, dim3(NBLK), dim3(256), 0, stream,
                       xs, vs, charges, W_in, b_in, W_v, We1, be1, We2, be2,
                       Wx, Wh1, bh1, out, ws);
}

// Round 11
// 260.267 us; speedup vs baseline: 1.9830x; 1.9830x over previous
//
#include <hip/hip_runtime.h>

#define BB 32
#define NN 256
#define NF 16

typedef _Float16 half4 __attribute__((ext_vector_type(4)));
typedef float f32x4 __attribute__((ext_vector_type(4)));

// ws layout (floats): ping-pong x/h/su/sv (R8 layout, proven)
#define X0_OFF 0
#define X1_OFF 32768
#define H0_OFF 65536
#define H1_OFF 196608
#define SU0_OFF 327680
#define SV0_OFF 458752
#define SU1_OFF 589824
#define SV1_OFF 720896
#define SU2_OFF 851968
#define SV2_OFF 983040

__device__ __forceinline__ float dot4(float4 a, float4 b, float acc) {
    acc = fmaf(a.x, b.x, acc); acc = fmaf(a.y, b.y, acc);
    acc = fmaf(a.z, b.z, acc); acc = fmaf(a.w, b.w, acc);
    return acc;
}

// init: h0 = relu(charges*W_in + b_in); pad x; su0/sv0 for layer 0. (R8 verbatim)
__global__ __launch_bounds__(256)
void init_kernel(const float* __restrict__ xs, const float* __restrict__ charges,
                 const float* __restrict__ W_in, const float* __restrict__ b_in,
                 const float* __restrict__ We1, const float* __restrict__ be1,
                 float* __restrict__ x0, float* __restrict__ h0,
                 float* __restrict__ su0, float* __restrict__ sv0) {
    __shared__ float sWs[256], sWd[256], sb1[NF];
    const int tid = threadIdx.x;
    sWs[tid] = We1[tid];
    sWd[tid] = We1[256 + tid];
    if (tid < NF) sb1[tid] = be1[tid];
    const int n = blockIdx.x * 256 + tid;
    const float c = charges[n];
    float h[NF];
#pragma unroll
    for (int f = 0; f < NF; ++f) {
        h[f] = fmaxf(fmaf(c, W_in[f], b_in[f]), 0.f);
        h0[n * NF + f] = h[f];
    }
    x0[n * 4 + 0] = xs[n * 3 + 0];
    x0[n * 4 + 1] = xs[n * 3 + 1];
    x0[n * 4 + 2] = xs[n * 3 + 2];
    x0[n * 4 + 3] = 0.f;
    __syncthreads();
#pragma unroll
    for (int k = 0; k < NF; ++k) {
        float u = 0.f, v = sb1[k];
#pragma unroll
        for (int f = 0; f < NF; ++f) {
            u = fmaf(h[f], sWs[f * NF + k], u);
            v = fmaf(h[f], sWd[f * NF + k], v);
        }
        su0[n * NF + k] = u;
        sv0[n * NF + k] = v;
    }
}

// 1024 blocks x 512 threads (8 waves). Block = (batch b, node-octet oct).
// Wave w: pair id p = w&3, tile-half hh = w>>2. Waves p and p+4 both serve
// dsts j0 = 8*oct+p, j1 = 8*oct+4+p; wave hh=0 does tiles 0..7, hh=1 does
// 8..15. Partials (Sw*, g*) combine via LDS before the epilogue (waves 0..3).
// Same total VALU work and L2 traffic as R8, but 32 waves/CU (VGPR<=64 via
// __launch_bounds__(512,8)) for 2x latency hiding — the R10 by-product
// showed this body fits 64 VGPRs.
// Per tile, per dst, one v_mfma_f32_16x16x16f16 (lane (g,c)):
//   A-frag: We2[k=4g+i][outfeat=c]  B-frag: m1[src=16t+c][k=4g+i]
//   C-frag: m-hat[outfeat=4g+r][src=c]; self-edge masked in g only
//   (w-path self-term cancels exactly in Sw*xj - Swx).
__global__ __launch_bounds__(512, 8)
void layer_kernel(const float* __restrict__ x_in, const float* __restrict__ h_in,
                  const float* __restrict__ su_in, const float* __restrict__ sv_in,
                  float* __restrict__ x_out, float* __restrict__ h_out,
                  float* __restrict__ su_out, float* __restrict__ sv_out,
                  const float* __restrict__ vs, const float* __restrict__ Wv_l,
                  const float* __restrict__ We1_l, const float* __restrict__ We2_l,
                  const float* __restrict__ be2_l, const float* __restrict__ Wx_l,
                  const float* __restrict__ Wh1_l, const float* __restrict__ bh1_l,
                  const float* __restrict__ We1_n, const float* __restrict__ be1_n,
                  int final_layer) {
    __shared__ float sWh1s[512];
    __shared__ float sWa[256];            // next-layer WsrcT
    __shared__ float sWb[256];            // next-layer WdstT
    __shared__ float sbe1n[NF];
    __shared__ float sh_new[8][NF + 1];
    __shared__ float sSw[2][8][4];        // [tile-half][slot][Sw,Swx,Swy,Swz]
    __shared__ float sg2[2][8][NF];       // [tile-half][slot][outfeat]

    const int tid  = threadIdx.x;
    const int b    = blockIdx.x >> 5;
    const int oct  = blockIdx.x & 31;
    const int n0l  = 8 * oct;
    const size_t n0 = (size_t)b * NN + n0l;
    const int w    = tid >> 6;
    const int lane = tid & 63;
    const int c    = lane & 15;
    const int g    = lane >> 4;
    const int p    = w & 3;       // dst-pair id
    const int hh   = w >> 2;      // tile half

    // stage epilogue/next-layer weights (consumed only after the post-loop sync)
    sWh1s[tid] = Wh1_l[tid];
    if (!final_layer && tid < 256) {
        const int f = tid >> 4, k = tid & 15;
        sWa[k * NF + f] = We1_n[tid];           // WsrcT
        sWb[k * NF + f] = We1_n[256 + tid];     // WdstT
        if (tid < NF) sbe1n[tid] = be1_n[tid];
    }

    // per-wave invariants for dsts j0, j1
    const int j0 = n0l + p, j1 = n0l + 4 + p;
    const float* x_b  = x_in + (size_t)b * NN * 4;
    const float* su_b = su_in + (size_t)b * NN * NF;
    const float4 xj0 = *(const float4*)(x_b + 4 * j0);
    const float4 xj1 = *(const float4*)(x_b + 4 * j1);
    half4 afrag;
    afrag.x = (_Float16)We2_l[(4 * g + 0) * NF + c];
    afrag.y = (_Float16)We2_l[(4 * g + 1) * NF + c];
    afrag.z = (_Float16)We2_l[(4 * g + 2) * NF + c];
    afrag.w = (_Float16)We2_l[(4 * g + 3) * NF + c];
    const float4 v40  = *(const float4*)(sv_in + ((size_t)b * NN + j0) * NF + 4 * g);
    const float4 v41  = *(const float4*)(sv_in + ((size_t)b * NN + j1) * NF + 4 * g);
    const float4 wr4  = *(const float4*)(We1_l + 512 + 4 * g);
    const float4 be2f = *(const float4*)(be2_l + 4 * g);
    const float4 wxf  = *(const float4*)(Wx_l + 4 * g);

    float Sw0 = 0.f, Swx0 = 0.f, Swy0 = 0.f, Swz0 = 0.f;
    float Sw1 = 0.f, Swx1 = 0.f, Swy1 = 0.f, Swz1 = 0.f;
    float g00 = 0.f, g01 = 0.f, g02 = 0.f, g03 = 0.f;
    float g10 = 0.f, g11 = 0.f, g12 = 0.f, g13 = 0.f;

    const float* su_p = su_b + c * NF + 4 * g;   // +256 floats per tile
    const float* x_p  = x_b + 4 * c;             // +64 floats per tile

#pragma unroll 2
    for (int tt = 0; tt < 8; ++tt) {
        const int t = 8 * hh + tt;
        const float4 u4  = *(const float4*)(su_p + 256 * t);
        const float4 xs4 = *(const float4*)(x_p + 64 * t);
        const f32x4 zc = {0.f, 0.f, 0.f, 0.f};
        const int s = 16 * t + c;
        // ---- dst 0 ----
        {
            const float dx = xj0.x - xs4.x, dy = xj0.y - xs4.y, dz = xj0.z - xs4.z;
            const float r2 = fmaf(dx, dx, fmaf(dy, dy, dz * dz));
            const float m0 = fmaxf(fmaf(r2, wr4.x, u4.x + v40.x), 0.f);
            const float m1 = fmaxf(fmaf(r2, wr4.y, u4.y + v40.y), 0.f);
            const float m2 = fmaxf(fmaf(r2, wr4.z, u4.z + v40.z), 0.f);
            const float m3 = fmaxf(fmaf(r2, wr4.w, u4.w + v40.w), 0.f);
            half4 bfrag;
            bfrag.x = (_Float16)m0; bfrag.y = (_Float16)m1;
            bfrag.z = (_Float16)m2; bfrag.w = (_Float16)m3;
            const f32x4 acc = __builtin_amdgcn_mfma_f32_16x16x16f16(afrag, bfrag, zc, 0, 0, 0);
            const float e0 = fmaxf(acc.x + be2f.x, 0.f);
            const float e1 = fmaxf(acc.y + be2f.y, 0.f);
            const float e2 = fmaxf(acc.z + be2f.z, 0.f);
            const float e3 = fmaxf(acc.w + be2f.w, 0.f);
            float wp = e0 * wxf.x;
            wp = fmaf(e1, wxf.y, wp);
            wp = fmaf(e2, wxf.z, wp);
            wp = fmaf(e3, wxf.w, wp);
            const float gsel = (s != j0) ? 1.f : 0.f;
            g00 = fmaf(e0, gsel, g00);
            g01 = fmaf(e1, gsel, g01);
            g02 = fmaf(e2, gsel, g02);
            g03 = fmaf(e3, gsel, g03);
            Sw0 += wp;
            Swx0 = fmaf(wp, xs4.x, Swx0);
            Swy0 = fmaf(wp, xs4.y, Swy0);
            Swz0 = fmaf(wp, xs4.z, Swz0);
        }
        // ---- dst 1 (reuses u4/xs4) ----
        {
            const float dx = xj1.x - xs4.x, dy = xj1.y - xs4.y, dz = xj1.z - xs4.z;
            const float r2 = fmaf(dx, dx, fmaf(dy, dy, dz * dz));
            const float m0 = fmaxf(fmaf(r2, wr4.x, u4.x + v41.x), 0.f);
            const float m1 = fmaxf(fmaf(r2, wr4.y, u4.y + v41.y), 0.f);
            const float m2 = fmaxf(fmaf(r2, wr4.z, u4.z + v41.z), 0.f);
            const float m3 = fmaxf(fmaf(r2, wr4.w, u4.w + v41.w), 0.f);
            half4 bfrag;
            bfrag.x = (_Float16)m0; bfrag.y = (_Float16)m1;
            bfrag.z = (_Float16)m2; bfrag.w = (_Float16)m3;
            const f32x4 acc = __builtin_amdgcn_mfma_f32_16x16x16f16(afrag, bfrag, zc, 0, 0, 0);
            const float e0 = fmaxf(acc.x + be2f.x, 0.f);
            const float e1 = fmaxf(acc.y + be2f.y, 0.f);
            const float e2 = fmaxf(acc.z + be2f.z, 0.f);
            const float e3 = fmaxf(acc.w + be2f.w, 0.f);
            float wp = e0 * wxf.x;
            wp = fmaf(e1, wxf.y, wp);
            wp = fmaf(e2, wxf.z, wp);
            wp = fmaf(e3, wxf.w, wp);
            const float gsel = (s != j1) ? 1.f : 0.f;
            g10 = fmaf(e0, gsel, g10);
            g11 = fmaf(e1, gsel, g11);
            g12 = fmaf(e2, gsel, g12);
            g13 = fmaf(e3, gsel, g13);
            Sw1 += wp;
            Swx1 = fmaf(wp, xs4.x, Swx1);
            Swy1 = fmaf(wp, xs4.y, Swy1);
            Swz1 = fmaf(wp, xs4.z, Swz1);
        }
    }

    // ---- in-wave reductions ----
#pragma unroll
    for (int off = 1; off < 64; off <<= 1) {
        Sw0  += __shfl_xor(Sw0,  off, 64);  Sw1  += __shfl_xor(Sw1,  off, 64);
        Swx0 += __shfl_xor(Swx0, off, 64);  Swx1 += __shfl_xor(Swx1, off, 64);
        Swy0 += __shfl_xor(Swy0, off, 64);  Swy1 += __shfl_xor(Swy1, off, 64);
        Swz0 += __shfl_xor(Swz0, off, 64);  Swz1 += __shfl_xor(Swz1, off, 64);
    }
#pragma unroll
    for (int off = 1; off < 16; off <<= 1) {
        g00 += __shfl_xor(g00, off, 64);  g10 += __shfl_xor(g10, off, 64);
        g01 += __shfl_xor(g01, off, 64);  g11 += __shfl_xor(g11, off, 64);
        g02 += __shfl_xor(g02, off, 64);  g12 += __shfl_xor(g12, off, 64);
        g03 += __shfl_xor(g03, off, 64);  g13 += __shfl_xor(g13, off, 64);
    }
    // stage per-half partials to LDS
    if (lane == 0) {
        sSw[hh][p][0] = Sw0;  sSw[hh][p][1] = Swx0;
        sSw[hh][p][2] = Swy0; sSw[hh][p][3] = Swz0;
        sSw[hh][p + 4][0] = Sw1;  sSw[hh][p + 4][1] = Swx1;
        sSw[hh][p + 4][2] = Swy1; sSw[hh][p + 4][3] = Swz1;
    }
    if ((lane & 15) == 0) {
        *(float4*)&sg2[hh][p][4 * g]     = make_float4(g00, g01, g02, g03);
        *(float4*)&sg2[hh][p + 4][4 * g] = make_float4(g10, g11, g12, g13);
    }
    __syncthreads();

    // ---- node epilogue (waves 0..3; lanes 0..15 -> j0, 32..47 -> j1) ----
    const int is0 = (w < 4) && (lane < 16);
    const int is1 = (w < 4) && (lane >= 32 && lane < 48);
    if (is0 || is1) {
        const int f = lane & 15;
        const int slot = is0 ? p : (p + 4);
        const int jm   = is0 ? j0 : j1;
        const float SwS = sSw[0][slot][0] + sSw[1][slot][0];
        const float SxS = sSw[0][slot][1] + sSw[1][slot][1];
        const float SyS = sSw[0][slot][2] + sSw[1][slot][2];
        const float SzS = sSw[0][slot][3] + sSw[1][slot][3];
        const float4 xjm = is0 ? xj0 : xj1;
        const size_t nj = (size_t)b * NN + jm;
        float hd = bh1_l[f];
        float hv = 0.f;
#pragma unroll
        for (int k = 0; k < NF; ++k) {
            const float hjk = h_in[nj * NF + k];
            hd = fmaf(hjk, sWh1s[k * NF + f], hd);
            hv = fmaf(hjk, Wv_l[k], hv);
        }
#pragma unroll
        for (int k = 0; k < NF; ++k) {
            hd = fmaf(sg2[0][slot][k] + sg2[1][slot][k], sWh1s[(NF + k) * NF + f], hd);
        }
        const float hnew = h_in[nj * NF + f] + fmaxf(hd, 0.f);
        sh_new[slot][f] = hnew;
        if (!final_layer) h_out[nj * NF + f] = hnew;
        if (f < 3) {
            const float xc = (f == 0) ? xjm.x : ((f == 1) ? xjm.y : xjm.z);
            const float Sc = (f == 0) ? SxS  : ((f == 1) ? SyS  : SzS);
            const float agg = (SwS * xc - Sc) * (1.f / 255.f);
            const float xnew = xc + agg + vs[nj * 3 + f] * hv;
            if (final_layer) x_out[nj * 3 + f] = xnew;
            else             x_out[nj * 4 + f] = xnew;
        }
        if (!final_layer && f == 3) x_out[nj * 4 + 3] = 0.f;
    }

    if (!final_layer) {
        __syncthreads();
        // su/sv for the NEXT layer (this block's 8 nodes; waves 0,1)
        if (tid < 128) {
            const int jd = tid >> 4, k = tid & 15;
            float u = 0.f, v = sbe1n[k];
#pragma unroll
            for (int f = 0; f < NF; ++f) {
                const float hf = sh_new[jd][f];
                u = fmaf(hf, sWa[k * NF + f], u);
                v = fmaf(hf, sWb[k * NF + f], v);
            }
            su_out[(n0 + jd) * NF + k] = u;
            sv_out[(n0 + jd) * NF + k] = v;
        }
    }
}

extern "C" void kernel_launch(void* const* d_in, const int* in_sizes, int n_in,
                              void* d_out, int out_size, void* d_ws, size_t ws_size,
                              hipStream_t stream) {
    const float* xs      = (const float*)d_in[0];
    const float* vs      = (const float*)d_in[1];
    const float* charges = (const float*)d_in[2];
    const float* W_in    = (const float*)d_in[3];
    const float* b_in    = (const float*)d_in[4];
    const float* W_v     = (const float*)d_in[5];
    const float* We1     = (const float*)d_in[6];
    const float* be1     = (const float*)d_in[7];
    const float* We2     = (const float*)d_in[8];
    const float* be2     = (const float*)d_in[9];
    const float* Wx      = (const float*)d_in[10];
    const float* Wh1     = (const float*)d_in[11];
    const float* bh1     = (const float*)d_in[12];
    // d_in[13]=src, d_in[14]=dst: fully-connected pattern, computed analytically.

    float* ws = (float*)d_ws;
    float* x0  = ws + X0_OFF;
    float* x1  = ws + X1_OFF;
    float* h0  = ws + H0_OFF;
    float* h1  = ws + H1_OFF;
    float* su0 = ws + SU0_OFF;
    float* sv0 = ws + SV0_OFF;
    float* su1 = ws + SU1_OFF;
    float* sv1 = ws + SV1_OFF;
    float* su2 = ws + SU2_OFF;
    float* sv2 = ws + SV2_OFF;
    float* out = (float*)d_out;

    hipLaunchKernelGGL(init_kernel, dim3(32), dim3(256), 0, stream,
                       xs, charges, W_in, b_in, We1, be1, x0, h0, su0, sv0);
    hipLaunchKernelGGL(layer_kernel, dim3(1024), dim3(512), 0, stream,
                       x0, h0, su0, sv0, x1, h1, su1, sv1,
                       vs, W_v + 0 * 16, We1 + 0 * 528, We2 + 0 * 256,
                       be2 + 0 * 16, Wx + 0 * 16, Wh1 + 0 * 512, bh1 + 0 * 16,
                       We1 + 1 * 528, be1 + 1 * 16, 0);
    hipLaunchKernelGGL(layer_kernel, dim3(1024), dim3(512), 0, stream,
                       x1, h1, su1, sv1, x0, h0, su2, sv2,
                       vs, W_v + 1 * 16, We1 + 1 * 528, We2 + 1 * 256,
                       be2 + 1 * 16, Wx + 1 * 16, Wh1 + 1 * 512, bh1 + 1 * 16,
                       We1 + 2 * 528, be1 + 2 * 16, 0);
    hipLaunchKernelGGL(layer_kernel, dim3(1024), dim3(512), 0, stream,
                       x0, h0, su2, sv2, out, h1, su1, sv1,
                       vs, W_v + 2 * 16, We1 + 2 * 528, We2 + 2 * 256,
                       be2 + 2 * 16, Wx + 2 * 16, Wh1 + 2 * 512, bh1 + 2 * 16,
                       We1 + 2 * 528, be1 + 2 * 16, 1);
}

// Round 12
// 141.448 us; speedup vs baseline: 3.6488x; 1.8400x over previous
//
#include <hip/hip_runtime.h>

#define BB 32
#define NN 256
#define NF 16

typedef _Float16 half4 __attribute__((ext_vector_type(4)));
typedef float f32x4 __attribute__((ext_vector_type(4)));

// ws layout (floats): ping-pong x/h/su/sv (R8 layout, proven)
#define X0_OFF 0
#define X1_OFF 32768
#define H0_OFF 65536
#define H1_OFF 196608
#define SU0_OFF 327680
#define SV0_OFF 458752
#define SU1_OFF 589824
#define SV1_OFF 720896
#define SU2_OFF 851968
#define SV2_OFF 983040

// init: h0 = relu(charges*W_in + b_in); pad x; su0/sv0 for layer 0. (R8 verbatim)
__global__ __launch_bounds__(256)
void init_kernel(const float* __restrict__ xs, const float* __restrict__ charges,
                 const float* __restrict__ W_in, const float* __restrict__ b_in,
                 const float* __restrict__ We1, const float* __restrict__ be1,
                 float* __restrict__ x0, float* __restrict__ h0,
                 float* __restrict__ su0, float* __restrict__ sv0) {
    __shared__ float sWs[256], sWd[256], sb1[NF];
    const int tid = threadIdx.x;
    sWs[tid] = We1[tid];
    sWd[tid] = We1[256 + tid];
    if (tid < NF) sb1[tid] = be1[tid];
    const int n = blockIdx.x * 256 + tid;
    const float c = charges[n];
    float h[NF];
#pragma unroll
    for (int f = 0; f < NF; ++f) {
        h[f] = fmaxf(fmaf(c, W_in[f], b_in[f]), 0.f);
        h0[n * NF + f] = h[f];
    }
    x0[n * 4 + 0] = xs[n * 3 + 0];
    x0[n * 4 + 1] = xs[n * 3 + 1];
    x0[n * 4 + 2] = xs[n * 3 + 2];
    x0[n * 4 + 3] = 0.f;
    __syncthreads();
#pragma unroll
    for (int k = 0; k < NF; ++k) {
        float u = 0.f, v = sb1[k];
#pragma unroll
        for (int f = 0; f < NF; ++f) {
            u = fmaf(h[f], sWs[f * NF + k], u);
            v = fmaf(h[f], sWd[f * NF + k], v);
        }
        su0[n * NF + k] = u;
        sv0[n * NF + k] = v;
    }
}

// 1024 blocks x 256 threads (R8 structure — VGPR 128 tier, proven no-spill).
// Block = (batch b, node-octet oct); wave w owns dsts j0=8*oct+w, j1=8*oct+4+w
// sharing each tile's u4/xs4 loads. R12 change: tile loop software-pipelined —
// tile t+1's u4/xs4 loads issue before tile t's compute, hiding ~200-cyc L2
// latency under the ~130-cyc 2-dst body. (t+1)&15 clamp avoids a tail branch.
// Per 16-src tile, per dst, one v_mfma_f32_16x16x16f16 (lane (g,c)):
//   A-frag: We2[k=4g+i][outfeat=c]  B-frag: m1[src=16t+c][k=4g+i]
//   C-frag: m-hat[outfeat=4g+r][src=c]; self-edge masked in g only
//   (w-path self-term cancels exactly in Sw*xj - Swx).
__global__ __launch_bounds__(256)
void layer_kernel(const float* __restrict__ x_in, const float* __restrict__ h_in,
                  const float* __restrict__ su_in, const float* __restrict__ sv_in,
                  float* __restrict__ x_out, float* __restrict__ h_out,
                  float* __restrict__ su_out, float* __restrict__ sv_out,
                  const float* __restrict__ vs, const float* __restrict__ Wv_l,
                  const float* __restrict__ We1_l, const float* __restrict__ We2_l,
                  const float* __restrict__ be2_l, const float* __restrict__ Wx_l,
                  const float* __restrict__ Wh1_l, const float* __restrict__ bh1_l,
                  const float* __restrict__ We1_n, const float* __restrict__ be1_n,
                  int final_layer) {
    __shared__ float sWh1s[512];
    __shared__ float sWa[256];            // next-layer WsrcT
    __shared__ float sWb[256];            // next-layer WdstT
    __shared__ float sbe1n[NF];
    __shared__ float sh_new[8][NF + 1];
    __shared__ float sg[8][NF];

    const int tid  = threadIdx.x;
    const int b    = blockIdx.x >> 5;
    const int oct  = blockIdx.x & 31;
    const int n0l  = 8 * oct;
    const size_t n0 = (size_t)b * NN + n0l;
    const int w    = tid >> 6;
    const int lane = tid & 63;
    const int c    = lane & 15;
    const int g    = lane >> 4;

    // stage epilogue/next-layer weights (consumed only after the post-loop sync)
    sWh1s[tid]       = Wh1_l[tid];
    sWh1s[256 + tid] = Wh1_l[256 + tid];
    if (!final_layer) {
        const int f = tid >> 4, k = tid & 15;
        sWa[k * NF + f] = We1_n[tid];           // WsrcT
        sWb[k * NF + f] = We1_n[256 + tid];     // WdstT
        if (tid < NF) sbe1n[tid] = be1_n[tid];
    }

    // per-wave invariants for dsts j0, j1
    const int j0 = n0l + w, j1 = n0l + 4 + w;
    const float* x_b  = x_in + (size_t)b * NN * 4;
    const float* su_b = su_in + (size_t)b * NN * NF;
    const float4 xj0 = *(const float4*)(x_b + 4 * j0);
    const float4 xj1 = *(const float4*)(x_b + 4 * j1);
    half4 afrag;
    afrag.x = (_Float16)We2_l[(4 * g + 0) * NF + c];
    afrag.y = (_Float16)We2_l[(4 * g + 1) * NF + c];
    afrag.z = (_Float16)We2_l[(4 * g + 2) * NF + c];
    afrag.w = (_Float16)We2_l[(4 * g + 3) * NF + c];
    const float4 v40  = *(const float4*)(sv_in + ((size_t)b * NN + j0) * NF + 4 * g);
    const float4 v41  = *(const float4*)(sv_in + ((size_t)b * NN + j1) * NF + 4 * g);
    const float4 wr4  = *(const float4*)(We1_l + 512 + 4 * g);
    const float4 be2f = *(const float4*)(be2_l + 4 * g);
    const float4 wxf  = *(const float4*)(Wx_l + 4 * g);

    float Sw0 = 0.f, Swx0 = 0.f, Swy0 = 0.f, Swz0 = 0.f;
    float Sw1 = 0.f, Swx1 = 0.f, Swy1 = 0.f, Swz1 = 0.f;
    float g00 = 0.f, g01 = 0.f, g02 = 0.f, g03 = 0.f;
    float g10 = 0.f, g11 = 0.f, g12 = 0.f, g13 = 0.f;

    const float* su_p = su_b + c * NF + 4 * g;   // +256 floats per tile
    const float* x_p  = x_b + 4 * c;             // +64 floats per tile

    // software pipeline: tile t+1 loads in flight during tile t compute
    float4 u4n  = *(const float4*)(su_p);
    float4 xs4n = *(const float4*)(x_p);

#pragma unroll 2
    for (int t = 0; t < 16; ++t) {
        const float4 u4  = u4n;
        const float4 xs4 = xs4n;
        const int tn = (t + 1) & 15;     // clamp: last iter redundantly reloads tile 0
        u4n  = *(const float4*)(su_p + 256 * tn);
        xs4n = *(const float4*)(x_p + 64 * tn);
        const f32x4 zc = {0.f, 0.f, 0.f, 0.f};
        const int s = 16 * t + c;
        // ---- dst 0 ----
        {
            const float dx = xj0.x - xs4.x, dy = xj0.y - xs4.y, dz = xj0.z - xs4.z;
            const float r2 = fmaf(dx, dx, fmaf(dy, dy, dz * dz));
            const float m0 = fmaxf(fmaf(r2, wr4.x, u4.x + v40.x), 0.f);
            const float m1 = fmaxf(fmaf(r2, wr4.y, u4.y + v40.y), 0.f);
            const float m2 = fmaxf(fmaf(r2, wr4.z, u4.z + v40.z), 0.f);
            const float m3 = fmaxf(fmaf(r2, wr4.w, u4.w + v40.w), 0.f);
            half4 bfrag;
            bfrag.x = (_Float16)m0; bfrag.y = (_Float16)m1;
            bfrag.z = (_Float16)m2; bfrag.w = (_Float16)m3;
            const f32x4 acc = __builtin_amdgcn_mfma_f32_16x16x16f16(afrag, bfrag, zc, 0, 0, 0);
            const float e0 = fmaxf(acc.x + be2f.x, 0.f);
            const float e1 = fmaxf(acc.y + be2f.y, 0.f);
            const float e2 = fmaxf(acc.z + be2f.z, 0.f);
            const float e3 = fmaxf(acc.w + be2f.w, 0.f);
            float wp = e0 * wxf.x;
            wp = fmaf(e1, wxf.y, wp);
            wp = fmaf(e2, wxf.z, wp);
            wp = fmaf(e3, wxf.w, wp);
            const float gsel = (s != j0) ? 1.f : 0.f;
            g00 = fmaf(e0, gsel, g00);
            g01 = fmaf(e1, gsel, g01);
            g02 = fmaf(e2, gsel, g02);
            g03 = fmaf(e3, gsel, g03);
            Sw0 += wp;
            Swx0 = fmaf(wp, xs4.x, Swx0);
            Swy0 = fmaf(wp, xs4.y, Swy0);
            Swz0 = fmaf(wp, xs4.z, Swz0);
        }
        // ---- dst 1 (reuses u4/xs4) ----
        {
            const float dx = xj1.x - xs4.x, dy = xj1.y - xs4.y, dz = xj1.z - xs4.z;
            const float r2 = fmaf(dx, dx, fmaf(dy, dy, dz * dz));
            const float m0 = fmaxf(fmaf(r2, wr4.x, u4.x + v41.x), 0.f);
            const float m1 = fmaxf(fmaf(r2, wr4.y, u4.y + v41.y), 0.f);
            const float m2 = fmaxf(fmaf(r2, wr4.z, u4.z + v41.z), 0.f);
            const float m3 = fmaxf(fmaf(r2, wr4.w, u4.w + v41.w), 0.f);
            half4 bfrag;
            bfrag.x = (_Float16)m0; bfrag.y = (_Float16)m1;
            bfrag.z = (_Float16)m2; bfrag.w = (_Float16)m3;
            const f32x4 acc = __builtin_amdgcn_mfma_f32_16x16x16f16(afrag, bfrag, zc, 0, 0, 0);
            const float e0 = fmaxf(acc.x + be2f.x, 0.f);
            const float e1 = fmaxf(acc.y + be2f.y, 0.f);
            const float e2 = fmaxf(acc.z + be2f.z, 0.f);
            const float e3 = fmaxf(acc.w + be2f.w, 0.f);
            float wp = e0 * wxf.x;
            wp = fmaf(e1, wxf.y, wp);
            wp = fmaf(e2, wxf.z, wp);
            wp = fmaf(e3, wxf.w, wp);
            const float gsel = (s != j1) ? 1.f : 0.f;
            g10 = fmaf(e0, gsel, g10);
            g11 = fmaf(e1, gsel, g11);
            g12 = fmaf(e2, gsel, g12);
            g13 = fmaf(e3, gsel, g13);
            Sw1 += wp;
            Swx1 = fmaf(wp, xs4.x, Swx1);
            Swy1 = fmaf(wp, xs4.y, Swy1);
            Swz1 = fmaf(wp, xs4.z, Swz1);
        }
    }

    // ---- out-of-loop reductions ----
#pragma unroll
    for (int off = 1; off < 64; off <<= 1) {
        Sw0  += __shfl_xor(Sw0,  off, 64);  Sw1  += __shfl_xor(Sw1,  off, 64);
        Swx0 += __shfl_xor(Swx0, off, 64);  Swx1 += __shfl_xor(Swx1, off, 64);
        Swy0 += __shfl_xor(Swy0, off, 64);  Swy1 += __shfl_xor(Swy1, off, 64);
        Swz0 += __shfl_xor(Swz0, off, 64);  Swz1 += __shfl_xor(Swz1, off, 64);
    }
#pragma unroll
    for (int off = 1; off < 16; off <<= 1) {
        g00 += __shfl_xor(g00, off, 64);  g10 += __shfl_xor(g10, off, 64);
        g01 += __shfl_xor(g01, off, 64);  g11 += __shfl_xor(g11, off, 64);
        g02 += __shfl_xor(g02, off, 64);  g12 += __shfl_xor(g12, off, 64);
        g03 += __shfl_xor(g03, off, 64);  g13 += __shfl_xor(g13, off, 64);
    }
    if ((lane & 15) == 0) {
        *(float4*)&sg[w][4 * g]     = make_float4(g00, g01, g02, g03);
        *(float4*)&sg[w + 4][4 * g] = make_float4(g10, g11, g12, g13);
    }
    __syncthreads();

    // node epilogue: lanes 0..15 -> j0 (slot w); lanes 32..47 -> j1 (slot w+4)
    const int is0 = (lane < 16);
    const int is1 = (lane >= 32 && lane < 48);
    if (is0 || is1) {
        const int f = lane & 15;
        const int slot = is0 ? w : (w + 4);
        const int jm   = is0 ? j0 : j1;
        const float SwS = is0 ? Sw0  : Sw1;
        const float SxS = is0 ? Swx0 : Swx1;
        const float SyS = is0 ? Swy0 : Swy1;
        const float SzS = is0 ? Swz0 : Swz1;
        const float4 xjm = is0 ? xj0 : xj1;
        const size_t nj = (size_t)b * NN + jm;
        float hd = bh1_l[f];
        float hv = 0.f;
#pragma unroll
        for (int k = 0; k < NF; ++k) {
            const float hjk = h_in[nj * NF + k];
            hd = fmaf(hjk, sWh1s[k * NF + f], hd);
            hv = fmaf(hjk, Wv_l[k], hv);
        }
#pragma unroll
        for (int k = 0; k < NF; ++k) {
            hd = fmaf(sg[slot][k], sWh1s[(NF + k) * NF + f], hd);
        }
        const float hnew = h_in[nj * NF + f] + fmaxf(hd, 0.f);
        sh_new[slot][f] = hnew;
        if (!final_layer) h_out[nj * NF + f] = hnew;
        if (f < 3) {
            const float xc = (f == 0) ? xjm.x : ((f == 1) ? xjm.y : xjm.z);
            const float Sc = (f == 0) ? SxS  : ((f == 1) ? SyS  : SzS);
            const float agg = (SwS * xc - Sc) * (1.f / 255.f);
            const float xnew = xc + agg + vs[nj * 3 + f] * hv;
            if (final_layer) x_out[nj * 3 + f] = xnew;
            else             x_out[nj * 4 + f] = xnew;
        }
        if (!final_layer && f == 3) x_out[nj * 4 + 3] = 0.f;
    }

    if (!final_layer) {
        __syncthreads();
        // su/sv for the NEXT layer (this block's 8 nodes)
        if (tid < 128) {
            const int jd = tid >> 4, k = tid & 15;
            float u = 0.f, v = sbe1n[k];
#pragma unroll
            for (int f = 0; f < NF; ++f) {
                const float hf = sh_new[jd][f];
                u = fmaf(hf, sWa[k * NF + f], u);
                v = fmaf(hf, sWb[k * NF + f], v);
            }
            su_out[(n0 + jd) * NF + k] = u;
            sv_out[(n0 + jd) * NF + k] = v;
        }
    }
}

extern "C" void kernel_launch(void* const* d_in, const int* in_sizes, int n_in,
                              void* d_out, int out_size, void* d_ws, size_t ws_size,
                              hipStream_t stream) {
    const float* xs      = (const float*)d_in[0];
    const float* vs      = (const float*)d_in[1];
    const float* charges = (const float*)d_in[2];
    const float* W_in    = (const float*)d_in[3];
    const float* b_in    = (const float*)d_in[4];
    const float* W_v     = (const float*)d_in[5];
    const float* We1     = (const float*)d_in[6];
    const float* be1     = (const float*)d_in[7];
    const float* We2     = (const float*)d_in[8];
    const float* be2     = (const float*)d_in[9];
    const float* Wx      = (const float*)d_in[10];
    const float* Wh1     = (const float*)d_in[11];
    const float* bh1     = (const float*)d_in[12];
    // d_in[13]=src, d_in[14]=dst: fully-connected pattern, computed analytically.

    float* ws = (float*)d_ws;
    float* x0  = ws + X0_OFF;
    float* x1  = ws + X1_OFF;
    float* h0  = ws + H0_OFF;
    float* h1  = ws + H1_OFF;
    float* su0 = ws + SU0_OFF;
    float* sv0 = ws + SV0_OFF;
    float* su1 = ws + SU1_OFF;
    float* sv1 = ws + SV1_OFF;
    float* su2 = ws + SU2_OFF;
    float* sv2 = ws + SV2_OFF;
    float* out = (float*)d_out;

    hipLaunchKernelGGL(init_kernel, dim3(32), dim3(256), 0, stream,
                       xs, charges, W_in, b_in, We1, be1, x0, h0, su0, sv0);
    hipLaunchKernelGGL(layer_kernel, dim3(1024), dim3(256), 0, stream,
                       x0, h0, su0, sv0, x1, h1, su1, sv1,
                       vs, W_v + 0 * 16, We1 + 0 * 528, We2 + 0 * 256,
                       be2 + 0 * 16, Wx + 0 * 16, Wh1 + 0 * 512, bh1 + 0 * 16,
                       We1 + 1 * 528, be1 + 1 * 16, 0);
    hipLaunchKernelGGL(layer_kernel, dim3(1024), dim3(256), 0, stream,
                       x1, h1, su1, sv1, x0, h0, su2, sv2,
                       vs, W_v + 1 * 16, We1 + 1 * 528, We2 + 1 * 256,
                       be2 + 1 * 16, Wx + 1 * 16, Wh1 + 1 * 512, bh1 + 1 * 16,
                       We1 + 2 * 528, be1 + 2 * 16, 0);
    hipLaunchKernelGGL(layer_kernel, dim3(1024), dim3(256), 0, stream,
                       x0, h0, su2, sv2, out, h1, su1, sv1,
                       vs, W_v + 2 * 16, We1 + 2 * 528, We2 + 2 * 256,
                       be2 + 2 * 16, Wx + 2 * 16, Wh1 + 2 * 512, bh1 + 2 * 16,
                       We1 + 2 * 528, be1 + 2 * 16, 1);
}

// Round 13
// 132.532 us; speedup vs baseline: 3.8943x; 1.0673x over previous
//
#include <hip/hip_runtime.h>

#define BB 32
#define NN 256
#define NF 16

typedef _Float16 half4 __attribute__((ext_vector_type(4)));
typedef float f32x4 __attribute__((ext_vector_type(4)));

// ws layout (floats): ping-pong x/h/su/sv (R8 layout, proven)
#define X0_OFF 0
#define X1_OFF 32768
#define H0_OFF 65536
#define H1_OFF 196608
#define SU0_OFF 327680
#define SV0_OFF 458752
#define SU1_OFF 589824
#define SV1_OFF 720896
#define SU2_OFF 851968
#define SV2_OFF 983040

__device__ __forceinline__ float dot4(float4 a, float4 b, float acc) {
    acc = fmaf(a.x, b.x, acc); acc = fmaf(a.y, b.y, acc);
    acc = fmaf(a.z, b.z, acc); acc = fmaf(a.w, b.w, acc);
    return acc;
}

// init (R13): 512 blocks x 256 thr; block = 16 nodes. Phase 1: thread (n,f)
// computes h = relu(c*W_in+b_in) -> LDS + h0. Phase 2: thread (n,k) computes
// u,v with 32 LDS-broadcast FMAs. Replaces R8's 32-block / 512-FMA-per-thread
// init (only 32 of 256 CUs busy) with a ~1.5 us full-device pass.
__global__ __launch_bounds__(256)
void init_kernel(const float* __restrict__ xs, const float* __restrict__ charges,
                 const float* __restrict__ W_in, const float* __restrict__ b_in,
                 const float* __restrict__ We1, const float* __restrict__ be1,
                 float* __restrict__ x0, float* __restrict__ h0,
                 float* __restrict__ su0, float* __restrict__ sv0) {
    __shared__ float sWs[256], sWd[256];
    __shared__ __align__(16) float sh[16][NF];
    __shared__ float sb1[NF];
    const int tid = threadIdx.x;
    const size_t n0 = (size_t)blockIdx.x * 16;      // first node of this block
    const int nl = tid >> 4;                        // local node 0..15
    const int k  = tid & 15;                        // feature / k index
    sWs[tid] = We1[tid];
    sWd[tid] = We1[256 + tid];
    if (tid < NF) sb1[tid] = be1[tid];
    {
        const float c = charges[n0 + nl];
        const float hf = fmaxf(fmaf(c, W_in[k], b_in[k]), 0.f);
        sh[nl][k] = hf;
        h0[(n0 + nl) * NF + k] = hf;
    }
    if (tid < 64) {
        const int jd = tid >> 2, q = tid & 3;
        x0[(n0 + jd) * 4 + q] = (q < 3) ? xs[(n0 + jd) * 3 + q] : 0.f;
    }
    __syncthreads();
    {
        const float4* hn = (const float4*)&sh[nl][0];
        const float4 h0q = hn[0], h1q = hn[1], h2q = hn[2], h3q = hn[3];
        float u = 0.f, v = sb1[k];
#pragma unroll
        for (int q = 0; q < 4; ++q) {
            const float4 hq = (q == 0) ? h0q : (q == 1) ? h1q : (q == 2) ? h2q : h3q;
            u = fmaf(hq.x, sWs[(4 * q + 0) * NF + k], u);
            u = fmaf(hq.y, sWs[(4 * q + 1) * NF + k], u);
            u = fmaf(hq.z, sWs[(4 * q + 2) * NF + k], u);
            u = fmaf(hq.w, sWs[(4 * q + 3) * NF + k], u);
            v = fmaf(hq.x, sWd[(4 * q + 0) * NF + k], v);
            v = fmaf(hq.y, sWd[(4 * q + 1) * NF + k], v);
            v = fmaf(hq.z, sWd[(4 * q + 2) * NF + k], v);
            v = fmaf(hq.w, sWd[(4 * q + 3) * NF + k], v);
        }
        su0[(n0 + nl) * NF + k] = u;
        sv0[(n0 + nl) * NF + k] = v;
    }
}

// R8 layer kernel VERBATIM (champion, 135.7 us total; no-spill at VGPR=128).
// 1024 blocks x 256 threads. Block = (batch b, node-octet oct); wave w owns
// dsts j0 = 8*oct+w and j1 = 8*oct+4+w, sharing each tile's u4/xs4 loads.
// Per 16-src tile, per dst, one v_mfma_f32_16x16x16f16 (lane (g,c)):
//   A-frag: We2[k=4g+i][outfeat=c]   B-frag: m1[src=16t+c][k=4g+i]
//   C-frag: m-hat[outfeat=4g+r][src=c]; self-edge masked in g only
//   (w-path self-term cancels exactly in Sw*xj - Swx).
__global__ __launch_bounds__(256)
void layer_kernel(const float* __restrict__ x_in, const float* __restrict__ h_in,
                  const float* __restrict__ su_in, const float* __restrict__ sv_in,
                  float* __restrict__ x_out, float* __restrict__ h_out,
                  float* __restrict__ su_out, float* __restrict__ sv_out,
                  const float* __restrict__ vs, const float* __restrict__ Wv_l,
                  const float* __restrict__ We1_l, const float* __restrict__ We2_l,
                  const float* __restrict__ be2_l, const float* __restrict__ Wx_l,
                  const float* __restrict__ Wh1_l, const float* __restrict__ bh1_l,
                  const float* __restrict__ We1_n, const float* __restrict__ be1_n,
                  int final_layer) {
    __shared__ float sWh1s[512];
    __shared__ float sWa[256];            // next-layer WsrcT
    __shared__ float sWb[256];            // next-layer WdstT
    __shared__ float sbe1n[NF];
    __shared__ float sh_new[8][NF + 1];
    __shared__ float sg[8][NF];

    const int tid  = threadIdx.x;
    const int b    = blockIdx.x >> 5;
    const int oct  = blockIdx.x & 31;
    const int n0l  = 8 * oct;
    const size_t n0 = (size_t)b * NN + n0l;
    const int w    = tid >> 6;
    const int lane = tid & 63;
    const int c    = lane & 15;
    const int g    = lane >> 4;

    // stage epilogue/next-layer weights (consumed only after the post-loop sync)
    sWh1s[tid]       = Wh1_l[tid];
    sWh1s[256 + tid] = Wh1_l[256 + tid];
    if (!final_layer) {
        const int f = tid >> 4, k = tid & 15;
        sWa[k * NF + f] = We1_n[tid];           // WsrcT
        sWb[k * NF + f] = We1_n[256 + tid];     // WdstT
        if (tid < NF) sbe1n[tid] = be1_n[tid];
    }

    // per-wave invariants for dsts j0, j1
    const int j0 = n0l + w, j1 = n0l + 4 + w;
    const float* x_b  = x_in + (size_t)b * NN * 4;
    const float* su_b = su_in + (size_t)b * NN * NF;
    const float4 xj0 = *(const float4*)(x_b + 4 * j0);
    const float4 xj1 = *(const float4*)(x_b + 4 * j1);
    half4 afrag;
    afrag.x = (_Float16)We2_l[(4 * g + 0) * NF + c];
    afrag.y = (_Float16)We2_l[(4 * g + 1) * NF + c];
    afrag.z = (_Float16)We2_l[(4 * g + 2) * NF + c];
    afrag.w = (_Float16)We2_l[(4 * g + 3) * NF + c];
    const float4 v40  = *(const float4*)(sv_in + ((size_t)b * NN + j0) * NF + 4 * g);
    const float4 v41  = *(const float4*)(sv_in + ((size_t)b * NN + j1) * NF + 4 * g);
    const float4 wr4  = *(const float4*)(We1_l + 512 + 4 * g);
    const float4 be2f = *(const float4*)(be2_l + 4 * g);
    const float4 wxf  = *(const float4*)(Wx_l + 4 * g);

    float Sw0 = 0.f, Swx0 = 0.f, Swy0 = 0.f, Swz0 = 0.f;
    float Sw1 = 0.f, Swx1 = 0.f, Swy1 = 0.f, Swz1 = 0.f;
    float g00 = 0.f, g01 = 0.f, g02 = 0.f, g03 = 0.f;
    float g10 = 0.f, g11 = 0.f, g12 = 0.f, g13 = 0.f;

    const float* su_p = su_b + c * NF + 4 * g;   // +256 floats per tile
    const float* x_p  = x_b + 4 * c;             // +64 floats per tile

#pragma unroll 2
    for (int t = 0; t < 16; ++t) {
        const float4 u4  = *(const float4*)(su_p + 256 * t);
        const float4 xs4 = *(const float4*)(x_p + 64 * t);
        const f32x4 zc = {0.f, 0.f, 0.f, 0.f};
        const int s = 16 * t + c;
        // ---- dst 0 ----
        {
            const float dx = xj0.x - xs4.x, dy = xj0.y - xs4.y, dz = xj0.z - xs4.z;
            const float r2 = fmaf(dx, dx, fmaf(dy, dy, dz * dz));
            const float m0 = fmaxf(fmaf(r2, wr4.x, u4.x + v40.x), 0.f);
            const float m1 = fmaxf(fmaf(r2, wr4.y, u4.y + v40.y), 0.f);
            const float m2 = fmaxf(fmaf(r2, wr4.z, u4.z + v40.z), 0.f);
            const float m3 = fmaxf(fmaf(r2, wr4.w, u4.w + v40.w), 0.f);
            half4 bfrag;
            bfrag.x = (_Float16)m0; bfrag.y = (_Float16)m1;
            bfrag.z = (_Float16)m2; bfrag.w = (_Float16)m3;
            const f32x4 acc = __builtin_amdgcn_mfma_f32_16x16x16f16(afrag, bfrag, zc, 0, 0, 0);
            const float e0 = fmaxf(acc.x + be2f.x, 0.f);
            const float e1 = fmaxf(acc.y + be2f.y, 0.f);
            const float e2 = fmaxf(acc.z + be2f.z, 0.f);
            const float e3 = fmaxf(acc.w + be2f.w, 0.f);
            float wp = e0 * wxf.x;
            wp = fmaf(e1, wxf.y, wp);
            wp = fmaf(e2, wxf.z, wp);
            wp = fmaf(e3, wxf.w, wp);
            const float gsel = (s != j0) ? 1.f : 0.f;
            g00 = fmaf(e0, gsel, g00);
            g01 = fmaf(e1, gsel, g01);
            g02 = fmaf(e2, gsel, g02);
            g03 = fmaf(e3, gsel, g03);
            Sw0 += wp;
            Swx0 = fmaf(wp, xs4.x, Swx0);
            Swy0 = fmaf(wp, xs4.y, Swy0);
            Swz0 = fmaf(wp, xs4.z, Swz0);
        }
        // ---- dst 1 (reuses u4/xs4) ----
        {
            const float dx = xj1.x - xs4.x, dy = xj1.y - xs4.y, dz = xj1.z - xs4.z;
            const float r2 = fmaf(dx, dx, fmaf(dy, dy, dz * dz));
            const float m0 = fmaxf(fmaf(r2, wr4.x, u4.x + v41.x), 0.f);
            const float m1 = fmaxf(fmaf(r2, wr4.y, u4.y + v41.y), 0.f);
            const float m2 = fmaxf(fmaf(r2, wr4.z, u4.z + v41.z), 0.f);
            const float m3 = fmaxf(fmaf(r2, wr4.w, u4.w + v41.w), 0.f);
            half4 bfrag;
            bfrag.x = (_Float16)m0; bfrag.y = (_Float16)m1;
            bfrag.z = (_Float16)m2; bfrag.w = (_Float16)m3;
            const f32x4 acc = __builtin_amdgcn_mfma_f32_16x16x16f16(afrag, bfrag, zc, 0, 0, 0);
            const float e0 = fmaxf(acc.x + be2f.x, 0.f);
            const float e1 = fmaxf(acc.y + be2f.y, 0.f);
            const float e2 = fmaxf(acc.z + be2f.z, 0.f);
            const float e3 = fmaxf(acc.w + be2f.w, 0.f);
            float wp = e0 * wxf.x;
            wp = fmaf(e1, wxf.y, wp);
            wp = fmaf(e2, wxf.z, wp);
            wp = fmaf(e3, wxf.w, wp);
            const float gsel = (s != j1) ? 1.f : 0.f;
            g10 = fmaf(e0, gsel, g10);
            g11 = fmaf(e1, gsel, g11);
            g12 = fmaf(e2, gsel, g12);
            g13 = fmaf(e3, gsel, g13);
            Sw1 += wp;
            Swx1 = fmaf(wp, xs4.x, Swx1);
            Swy1 = fmaf(wp, xs4.y, Swy1);
            Swz1 = fmaf(wp, xs4.z, Swz1);
        }
    }

    // ---- out-of-loop reductions ----
#pragma unroll
    for (int off = 1; off < 64; off <<= 1) {
        Sw0  += __shfl_xor(Sw0,  off, 64);  Sw1  += __shfl_xor(Sw1,  off, 64);
        Swx0 += __shfl_xor(Swx0, off, 64);  Swx1 += __shfl_xor(Swx1, off, 64);
        Swy0 += __shfl_xor(Swy0, off, 64);  Swy1 += __shfl_xor(Swy1, off, 64);
        Swz0 += __shfl_xor(Swz0, off, 64);  Swz1 += __shfl_xor(Swz1, off, 64);
    }
#pragma unroll
    for (int off = 1; off < 16; off <<= 1) {
        g00 += __shfl_xor(g00, off, 64);  g10 += __shfl_xor(g10, off, 64);
        g01 += __shfl_xor(g01, off, 64);  g11 += __shfl_xor(g11, off, 64);
        g02 += __shfl_xor(g02, off, 64);  g12 += __shfl_xor(g12, off, 64);
        g03 += __shfl_xor(g03, off, 64);  g13 += __shfl_xor(g13, off, 64);
    }
    if ((lane & 15) == 0) {
        *(float4*)&sg[w][4 * g]     = make_float4(g00, g01, g02, g03);
        *(float4*)&sg[w + 4][4 * g] = make_float4(g10, g11, g12, g13);
    }
    __syncthreads();

    // node epilogue: lanes 0..15 -> j0 (slot w); lanes 32..47 -> j1 (slot w+4)
    const int is0 = (lane < 16);
    const int is1 = (lane >= 32 && lane < 48);
    if (is0 || is1) {
        const int f = lane & 15;
        const int slot = is0 ? w : (w + 4);
        const int jm   = is0 ? j0 : j1;
        const float SwS = is0 ? Sw0  : Sw1;
        const float SxS = is0 ? Swx0 : Swx1;
        const float SyS = is0 ? Swy0 : Swy1;
        const float SzS = is0 ? Swz0 : Swz1;
        const float4 xjm = is0 ? xj0 : xj1;
        const size_t nj = (size_t)b * NN + jm;
        float hd = bh1_l[f];
        float hv = 0.f;
#pragma unroll
        for (int k = 0; k < NF; ++k) {
            const float hjk = h_in[nj * NF + k];
            hd = fmaf(hjk, sWh1s[k * NF + f], hd);
            hv = fmaf(hjk, Wv_l[k], hv);
        }
#pragma unroll
        for (int k = 0; k < NF; ++k) {
            hd = fmaf(sg[slot][k], sWh1s[(NF + k) * NF + f], hd);
        }
        const float hnew = h_in[nj * NF + f] + fmaxf(hd, 0.f);
        sh_new[slot][f] = hnew;
        if (!final_layer) h_out[nj * NF + f] = hnew;
        if (f < 3) {
            const float xc = (f == 0) ? xjm.x : ((f == 1) ? xjm.y : xjm.z);
            const float Sc = (f == 0) ? SxS  : ((f == 1) ? SyS  : SzS);
            const float agg = (SwS * xc - Sc) * (1.f / 255.f);
            const float xnew = xc + agg + vs[nj * 3 + f] * hv;
            if (final_layer) x_out[nj * 3 + f] = xnew;
            else             x_out[nj * 4 + f] = xnew;
        }
        if (!final_layer && f == 3) x_out[nj * 4 + 3] = 0.f;
    }

    if (!final_layer) {
        __syncthreads();
        // su/sv for the NEXT layer (this block's 8 nodes)
        if (tid < 128) {
            const int jd = tid >> 4, k = tid & 15;
            float u = 0.f, v = sbe1n[k];
#pragma unroll
            for (int f = 0; f < NF; ++f) {
                const float hf = sh_new[jd][f];
                u = fmaf(hf, sWa[k * NF + f], u);
                v = fmaf(hf, sWb[k * NF + f], v);
            }
            su_out[(n0 + jd) * NF + k] = u;
            sv_out[(n0 + jd) * NF + k] = v;
        }
    }
}

extern "C" void kernel_launch(void* const* d_in, const int* in_sizes, int n_in,
                              void* d_out, int out_size, void* d_ws, size_t ws_size,
                              hipStream_t stream) {
    const float* xs      = (const float*)d_in[0];
    const float* vs      = (const float*)d_in[1];
    const float* charges = (const float*)d_in[2];
    const float* W_in    = (const float*)d_in[3];
    const float* b_in    = (const float*)d_in[4];
    const float* W_v     = (const float*)d_in[5];
    const float* We1     = (const float*)d_in[6];
    const float* be1     = (const float*)d_in[7];
    const float* We2     = (const float*)d_in[8];
    const float* be2     = (const float*)d_in[9];
    const float* Wx      = (const float*)d_in[10];
    const float* Wh1     = (const float*)d_in[11];
    const float* bh1     = (const float*)d_in[12];
    // d_in[13]=src, d_in[14]=dst: fully-connected pattern, computed analytically.

    float* ws = (float*)d_ws;
    float* x0  = ws + X0_OFF;
    float* x1  = ws + X1_OFF;
    float* h0  = ws + H0_OFF;
    float* h1  = ws + H1_OFF;
    float* su0 = ws + SU0_OFF;
    float* sv0 = ws + SV0_OFF;
    float* su1 = ws + SU1_OFF;
    float* sv1 = ws + SV1_OFF;
    float* su2 = ws + SU2_OFF;
    float* sv2 = ws + SV2_OFF;
    float* out = (float*)d_out;

    hipLaunchKernelGGL(init_kernel, dim3(512), dim3(256), 0, stream,
                       xs, charges, W_in, b_in, We1, be1, x0, h0, su0, sv0);
    hipLaunchKernelGGL(layer_kernel, dim3(1024), dim3(256), 0, stream,
                       x0, h0, su0, sv0, x1, h1, su1, sv1,
                       vs, W_v + 0 * 16, We1 + 0 * 528, We2 + 0 * 256,
                       be2 + 0 * 16, Wx + 0 * 16, Wh1 + 0 * 512, bh1 + 0 * 16,
                       We1 + 1 * 528, be1 + 1 * 16, 0);
    hipLaunchKernelGGL(layer_kernel, dim3(1024), dim3(256), 0, stream,
                       x1, h1, su1, sv1, x0, h0, su2, sv2,
                       vs, W_v + 1 * 16, We1 + 1 * 528, We2 + 1 * 256,
                       be2 + 1 * 16, Wx + 1 * 16, Wh1 + 1 * 512, bh1 + 1 * 16,
                       We1 + 2 * 528, be1 + 2 * 16, 0);
    hipLaunchKernelGGL(layer_kernel, dim3(1024), dim3(256), 0, stream,
                       x0, h0, su2, sv2, out, h1, su1, sv1,
                       vs, W_v + 2 * 16, We1 + 2 * 528, We2 + 2 * 256,
                       be2 + 2 * 16, Wx + 2 * 16, Wh1 + 2 * 512, bh1 + 2 * 16,
                       We1 + 2 * 528, be1 + 2 * 16, 1);
}